// Round 7
// baseline (1085.763 us; speedup 1.0000x reference)
//
#include <hip/hip_runtime.h>
#include <hip/hip_cooperative_groups.h>

namespace cg = cooperative_groups;

#define NZg  512
#define NXg  512
#define NT   1200
#define NSRC 4
#define NREC 512
#define DTC  0.001f
#define DHC  10.0f

#define TZ     16            // interior tile rows per block
#define TX     32            // interior tile cols per block
#define KK     16            // substeps per batch (= halo width), even
#define EZ     48            // extended rows = TZ + 2*KK
#define EX     64            // extended cols = TX + 2*KK
#define EZP    50            // EZ + 2 zero pad rows
#define NBATCH 75            // NT / KK
#define NTH    256           // 4 waves per block, 2 blocks per CU
#define NBZ    32            // block grid z
#define NBX    16            // block grid x
#define NBLK   512

typedef unsigned long long u64;

// Relaxed agent-scope atomics: plain global_load/store with sc0|sc1
// (bypass L1 + non-coherent per-XCD L2; coherent at memory-side L3).
__device__ __forceinline__ u64 ld_agent(const u64* p) {
    return __hip_atomic_load(p, __ATOMIC_RELAXED, __HIP_MEMORY_SCOPE_AGENT);
}
__device__ __forceinline__ void st_agent(u64* p, u64 v) {
    __hip_atomic_store(p, v, __ATOMIC_RELAXED, __HIP_MEMORY_SCOPE_AGENT);
}
__device__ __forceinline__ u64 pack2(float a, float b) {
    union { float f[2]; u64 u; } c; c.f[0] = a; c.f[1] = b; return c.u;
}
__device__ __forceinline__ float2 unpack2(u64 v) {
    union { u64 u; float f[2]; } c; c.u = v; return make_float2(c.f[0], c.f[1]);
}

// Temporal-blocked FDTD, p2p neighbor flag sync, fence-free, TWO independent
// workgroups per CU (separate barrier groups -> substep latency of one tile
// hides under the other's compute). 512 blocks (32x16 tiles of 16x32) x 256
// threads; patch = 4 wide x 3 tall (12 cells/thread).
__global__ __launch_bounds__(NTH, 2)
void wave_tlp(const float* __restrict__ xsrc,   // (NSRC, NT)
              const float* __restrict__ vel,    // (NZ, NX)
              const int*   __restrict__ src_z,
              const int*   __restrict__ src_x,
              const int*   __restrict__ rec_z,
              const int*   __restrict__ rec_x,
              float*       __restrict__ out,    // (NT, NREC)
              u64*         __restrict__ slot0,  // (cur, prev) per cell
              u64*         __restrict__ slot1,
              int*         __restrict__ flags)  // (512)
{
    cg::grid_group grid = cg::this_grid();

    __shared__ float sA[EZP * EX];
    __shared__ float sB[EZP * EX];
    __shared__ float sx[NSRC * NT];
    __shared__ int   recl[NREC];
    __shared__ int   nrec_s;

    const int tid = threadIdx.x;
    const int me  = blockIdx.x;
    const int bz  = me >> 4, bx = me & 15;     // 32 x 16 block grid
    const int oz  = bz * TZ - KK;
    const int ox  = bx * TX - KK;
    const int pc  = tid & 15;        // patch column: cells 4pc .. 4pc+3
    const int pr  = tid >> 4;        // patch row block: rows 3pr .. 3pr+2
    const int lx  = 4 * pc;
    const int z0  = 3 * pr;
    const int gx  = ox + lx;
    const int gz0 = oz + z0;

    // Reset my flag (stale values survive between graph replays).
    if (tid == 0) { flags[me] = 0; nrec_s = 0; }

    // Zero LDS padding rows (rows 0 and EZP-1 of both buffers) once.
    if (tid < 2 * EX) {
        const int r = (tid < EX) ? 0 : (EZP - 1);
        const int c = tid & (EX - 1);
        sA[r * EX + c] = 0.f;  sB[r * EX + c] = 0.f;
    }
    // Stage source traces in LDS.
    for (int i = tid; i < NSRC * NT; i += NTH) sx[i] = xsrc[i];
    __syncthreads();

    // Receiver list for this block's interior.
    for (int r = tid; r < NREC; r += NTH) {
        const int rz = rec_z[r], rx = rec_x[r];
        if (rz >= bz * TZ && rz < bz * TZ + TZ &&
            rx >= bx * TX && rx < bx * TX + TX) {
            const int lzp = rz - oz + 1;          // padded row (17..33)
            const int lxx = rx - ox;              // 16..47
            const int s = atomicAdd(&nrec_s, 1);
            recl[s] = (r << 16) | (lzp << 8) | lxx;
        }
    }

    // Per-cell coefficients (coef=0 out-of-domain pins those cells to 0)
    // and source bitmask: bit ((i*4+k)*4 + s), row i, col k.
    float4 c0 = make_float4(0.f, 0.f, 0.f, 0.f);
    float4 c1 = c0, c2 = c0;
    u64 smask = 0ull;
    {
        int szr[NSRC], sxr[NSRC];
#pragma unroll
        for (int s = 0; s < NSRC; ++s) { szr[s] = src_z[s]; sxr[s] = src_x[s]; }
        float* cc[3] = {&c0.x, &c1.x, &c2.x};
#pragma unroll
        for (int i = 0; i < 3; ++i) {
            const int gz = gz0 + i;
            const bool okz = (gz >= 0 && gz < NZg);
#pragma unroll
            for (int k = 0; k < 4; ++k) {
                const int gxk = gx + k;
                if (okz && gxk >= 0 && gxk < NXg) {
                    const float v = vel[gz * NXg + gxk];
                    cc[i][k] = (v * DTC) * (v * DTC) / (DHC * DHC);
#pragma unroll
                    for (int s = 0; s < NSRC; ++s)
                        if (szr[s] == gz && sxr[s] == gxk)
                            smask |= 1ull << ((i * 4 + k) * 4 + s);
                }
            }
        }
    }
    __syncthreads();
    grid.sync();                 // flags reset everywhere; the ONLY grid sync

    float4 own0, own1, own2, prv0, prv1, prv2;
    const int cb0 = (z0 + 1) * EX + lx;          // padded LDS index, row 0
    const int cb1 = cb0 + EX;
    const int cb2 = cb1 + EX;

    // Neighbor for my spin lane (threads 0..8, skip 4 = self).
    bool havenb = false; int nbidx = 0;
    if (tid < 9 && tid != 4) {
        const int nz = bz + tid / 3 - 1, nx = bx + tid % 3 - 1;
        havenb = (nz >= 0 && nz < NBZ && nx >= 0 && nx < NBX);
        nbidx  = nz * NBX + nx;
    }

    // One leapfrog substep: read src_, write dst_, then receivers gather.
    auto STEP = [&](float* __restrict__ dst_, const float* __restrict__ src_,
                    int t) {
        const float4 U  = *(const float4*)&src_[cb0 - EX];
        const float4 D  = *(const float4*)&src_[cb2 + EX];
        const float  l0 = src_[cb0 - 1], r0v = src_[cb0 + 4];
        const float  l1 = src_[cb1 - 1], r1v = src_[cb1 + 4];
        const float  l2 = src_[cb2 - 1], r2v = src_[cb2 + 4];

        float4 n0, n1, n2;
        n0.x = 2.f * own0.x - prv0.x + c0.x * (U.x + own1.x + l0     + own0.y - 4.f * own0.x);
        n0.y = 2.f * own0.y - prv0.y + c0.y * (U.y + own1.y + own0.x + own0.z - 4.f * own0.y);
        n0.z = 2.f * own0.z - prv0.z + c0.z * (U.z + own1.z + own0.y + own0.w - 4.f * own0.z);
        n0.w = 2.f * own0.w - prv0.w + c0.w * (U.w + own1.w + own0.z + r0v    - 4.f * own0.w);

        n1.x = 2.f * own1.x - prv1.x + c1.x * (own0.x + own2.x + l1     + own1.y - 4.f * own1.x);
        n1.y = 2.f * own1.y - prv1.y + c1.y * (own0.y + own2.y + own1.x + own1.z - 4.f * own1.y);
        n1.z = 2.f * own1.z - prv1.z + c1.z * (own0.z + own2.z + own1.y + own1.w - 4.f * own1.z);
        n1.w = 2.f * own1.w - prv1.w + c1.w * (own0.w + own2.w + own1.z + r1v    - 4.f * own1.w);

        n2.x = 2.f * own2.x - prv2.x + c2.x * (own1.x + D.x + l2     + own2.y - 4.f * own2.x);
        n2.y = 2.f * own2.y - prv2.y + c2.y * (own1.y + D.y + own2.x + own2.z - 4.f * own2.y);
        n2.z = 2.f * own2.z - prv2.z + c2.z * (own1.z + D.z + own2.y + own2.w - 4.f * own2.z);
        n2.w = 2.f * own2.w - prv2.w + c2.w * (own1.w + D.w + own2.z + r2v    - 4.f * own2.w);

        if (smask) {
            float* pn[3] = {&n0.x, &n1.x, &n2.x};
#pragma unroll
            for (int s = 0; s < NSRC; ++s) {
                const float amp = sx[s * NT + t];
#pragma unroll
                for (int i = 0; i < 3; ++i)
#pragma unroll
                    for (int k = 0; k < 4; ++k)
                        if (smask & (1ull << ((i * 4 + k) * 4 + s)))
                            pn[i][k] += amp;
            }
        }

        *(float4*)&dst_[cb0] = n0;
        *(float4*)&dst_[cb1] = n1;
        *(float4*)&dst_[cb2] = n2;
        prv0 = own0;  prv1 = own1;  prv2 = own2;
        own0 = n0;    own1 = n1;    own2 = n2;
        __syncthreads();
        for (int r = tid; r < nrec_s; r += NTH) {
            const int e = recl[r];
            out[t * NREC + (e >> 16)] = dst_[((e >> 8) & 0xFF) * EX + (e & 0xFF)];
        }
    };

    for (int b = 0; b < NBATCH; ++b) {
        const u64* gin  = (b & 1) ? slot1 : slot0;
        u64*       gout = (b & 1) ? slot0 : slot1;

        // ---- wait for the 8 neighbors to have finished batch b-1 ----
        if (b > 0) {
            if (havenb) {
                while (__hip_atomic_load(&flags[nbidx], __ATOMIC_RELAXED,
                                         __HIP_MEMORY_SCOPE_AGENT) < b)
                    __builtin_amdgcn_s_sleep(1);
            }
            __syncthreads();     // spin result broadcast; compiler barrier
        }

        // ---- load extended tile into sB + registers (agent atomics) ----
        {
            float* po[3] = {&own0.x, &own1.x, &own2.x};
            float* pp[3] = {&prv0.x, &prv1.x, &prv2.x};
#pragma unroll
            for (int i = 0; i < 3; ++i) {
                const int gz = gz0 + i;
                const bool okz = (gz >= 0 && gz < NZg);
#pragma unroll
                for (int k = 0; k < 4; ++k) {
                    const int gxk = gx + k;
                    if (b > 0 && okz && gxk >= 0 && gxk < NXg) {
                        const float2 v = unpack2(ld_agent(&gin[gz * NXg + gxk]));
                        po[i][k] = v.x;  pp[i][k] = v.y;
                    } else { po[i][k] = 0.f;  pp[i][k] = 0.f; }
                }
            }
        }
        *(float4*)&sB[cb0] = own0;
        *(float4*)&sB[cb1] = own1;
        *(float4*)&sB[cb2] = own2;
        __syncthreads();

        // ---- KK substeps, statically ping-ponged ----
        for (int j = 0; j < KK; j += 2) {
            STEP(sA, sB, b * KK + j);
            STEP(sB, sA, b * KK + j + 1);
        }

        // ---- write back 16x32 interior: lz in [16,32), pc in [4,12) ----
        if (pc >= 4 && pc < 12) {
            const float* po[3] = {&own0.x, &own1.x, &own2.x};
            const float* pp[3] = {&prv0.x, &prv1.x, &prv2.x};
#pragma unroll
            for (int i = 0; i < 3; ++i) {
                const int lz = z0 + i;
                if (lz >= KK && lz < KK + TZ) {
                    const int gz = oz + lz;
#pragma unroll
                    for (int k = 0; k < 4; ++k)
                        st_agent(&gout[gz * NXg + gx + k],
                                 pack2(po[i][k], pp[i][k]));
                }
            }
        }
        __syncthreads();         // every wave drains vmcnt before s_barrier
        if (tid == 0) {          // publish: data is globally visible already
            __hip_atomic_store(&flags[me], b + 1, __ATOMIC_RELAXED,
                               __HIP_MEMORY_SCOPE_AGENT);
        }
    }
}

extern "C" void kernel_launch(void* const* d_in, const int* in_sizes, int n_in,
                              void* d_out, int out_size, void* d_ws, size_t ws_size,
                              hipStream_t stream) {
    const float* xsrc  = (const float*)d_in[0];
    const float* vel   = (const float*)d_in[1];
    const int*   src_z = (const int*)  d_in[2];
    const int*   src_x = (const int*)  d_in[3];
    const int*   rec_z = (const int*)  d_in[4];
    const int*   rec_x = (const int*)  d_in[5];
    float*       out   = (float*)d_out;

    u64* slot0 = (u64*)d_ws;
    u64* slot1 = slot0 + NZg * NXg;
    int* flags = (int*)(slot1 + NZg * NXg);

    void* args[] = {(void*)&xsrc, (void*)&vel, (void*)&src_z, (void*)&src_x,
                    (void*)&rec_z, (void*)&rec_x, (void*)&out,
                    (void*)&slot0, (void*)&slot1, (void*)&flags};

    dim3 grid(NBLK), block(NTH);
    hipLaunchCooperativeKernel((const void*)wave_tlp, grid, block, args, 0, stream);
}